// Round 22
// baseline (82.995 us; speedup 1.0000x reference)
//
#include <hip/hip_runtime.h>
#include <stdint.h>

// Blocksparse Deep ReLU GAM forward via chained f16 MFMA — SINGLE KERNEL.
// 128 towers, each 2->16->12->8->1 MLP over input pair (2t, 2t+1);
// out[s] = sum_t tower_t(x[s]) + bias. shape_loss output = zeros(128).
//
// v_mfma_f32_16x16x16_f16 D layout (row=(lane>>4)*4+reg, col=lane&15)
// equals the B layout (k=(lane>>4)*4+i, col=lane&15), so Y = W·X chains
// layer-to-layer with only lane-local relu + f32->f16 cvt.
//
// Round 22: fuse out the pack kernel. r18-r21 plateaued at ~29.2us with
// every in-kernel lever falsified; the untested cost is the serial
// pack_frags dispatch (+launch gap, est 4-7us of the total). Each lane
// can gather its own A-fragments directly from the raw weights with
// aligned float2/float4 loads (a1: one float4 from a W1 row; a2/a3/
// c1/c2 similar; a0: float2+scalar, exec-masked). +4 loads/tower/lane,
// L2/L3-resident, once per block — in exchange for deleting a serial
// dispatch. Weight cvt uses (_Float16) casts (RTN), bit-identical to
// the pack path -> absmax unchanged. Out-zeroing via hipMemsetAsync;
// sum(b3)+bias wave-reduced per g==0 block.
//
// Proven structure kept from r20: oct_chain 8-way lockstep ILP, same-g
// blocks (L1 weight reuse), rolled pack loop (liveness fence),
// launch_bounds(256,4), named scalars/structs only (rule #20).
//
// 4-tower shared B0: lane (kg,col) carries B0 rows 4kg..4kg+2 =
// {x[s][2(tb+kg)], x[s][2(tb+kg)+1], 1}; tower tb+j's A0 is nonzero only
// in k-columns 4j..4j+2, so one coalesced all-lane x load feeds 4 towers.
//
// Bias: b0 -> A0 k=4j+2 (homogeneous coord); b1 -> C of L1 MFMA;
// b2 -> C of L2 MFMA; sum_t b3[t] + bias -> one scalar at the end.

constexpr int BATCH = 32768;
constexpr int FEAT  = 256;
constexpr int NTOW  = 128;

typedef _Float16 h4_t __attribute__((ext_vector_type(4)));
typedef __fp16   hp2_t __attribute__((ext_vector_type(2)));
typedef float    f4_t __attribute__((ext_vector_type(4)));

// f32x4 -> f16x4 via round-to-nearest casts (matches the old pack_frags
// conversion exactly -> bit-identical weights -> absmax parity).
static __device__ __forceinline__ h4_t cvt4n(const float4 v) {
  h4_t r;
  r[0] = (_Float16)v.x; r[1] = (_Float16)v.y;
  r[2] = (_Float16)v.z; r[3] = (_Float16)v.w;
  return r;
}
// pack 4 f32 -> 4 f16 (2x v_cvt_pkrtz) then packed relu (v_pk_max_f16 x2).
// relu(cvt(x)) == cvt(relu(x)): RTZ preserves sign; -0 is harmless in dots.
static __device__ __forceinline__ h4_t relu_pack4(const f4_t d) {
  const hp2_t lo = __builtin_amdgcn_cvt_pkrtz(d[0], d[1]);
  const hp2_t hi = __builtin_amdgcn_cvt_pkrtz(d[2], d[3]);
  h4_t r;
  r[0] = (_Float16)lo[0]; r[1] = (_Float16)lo[1];
  r[2] = (_Float16)hi[0]; r[3] = (_Float16)hi[1];
  const h4_t z = {(_Float16)0.f, (_Float16)0.f, (_Float16)0.f, (_Float16)0.f};
  return __builtin_elementwise_max(r, z);
}
// Build a B0 fragment from an x pair: {x0, x1, 1, 0}.
static __device__ __forceinline__ h4_t make_b0(const float* __restrict__ p) {
  const float2 xv = *(const float2*)p;
  const hp2_t xh = __builtin_amdgcn_cvt_pkrtz(xv.x, xv.y);
  h4_t b;
  b[0] = (_Float16)xh[0]; b[1] = (_Float16)xh[1];
  b[2] = (_Float16)1.0f;  b[3] = (_Float16)0.0f;
  return b;
}

// One tower's per-lane fragment set, gathered directly from raw weights.
struct TW { h4_t a0, a1, a2, a3; f4_t c1, c2; };

static __device__ __forceinline__ TW gather_tower(
    int t, int row, int kg,
    const float* __restrict__ W0, const float* __restrict__ B0,
    const float* __restrict__ W1, const float* __restrict__ B1,
    const float* __restrict__ W2, const float* __restrict__ B2,
    const float* __restrict__ W3) {
  TW w;
  // a0: tower t occupies k-columns 4*(t&3)..4*(t&3)+2 of the shared B0.
  float a00 = 0.f, a01 = 0.f, a02 = 0.f;
  if (kg == (t & 3)) {
    const float2 w0 = *(const float2*)&W0[(16*t + row) * FEAT + 2*t];
    a00 = w0.x; a01 = w0.y; a02 = B0[16*t + row];
  }
  w.a0[0] = (_Float16)a00; w.a0[1] = (_Float16)a01;
  w.a0[2] = (_Float16)a02; w.a0[3] = (_Float16)0.f;

  // a1: W1 rows 12t..12t+11, k-cols 16t+4kg..+3 (16B-aligned float4).
  float4 v1 = {0.f, 0.f, 0.f, 0.f};
  if (row < 12) v1 = *(const float4*)&W1[(12*t + row) * (16*NTOW) + 16*t + 4*kg];
  w.a1 = cvt4n(v1);

  // a2: W2 rows 8t..8t+7, k-cols 12t+4kg..+3 (k<12 -> kg<3).
  float4 v2 = {0.f, 0.f, 0.f, 0.f};
  if (row < 8 && kg < 3) v2 = *(const float4*)&W2[(8*t + row) * (12*NTOW) + 12*t + 4*kg];
  w.a2 = cvt4n(v2);

  // a3: W3 row 0 only, k-cols 8t+4kg..+3 (k<8 -> kg<2).
  float4 v3 = {0.f, 0.f, 0.f, 0.f};
  if (row == 0 && kg < 2) v3 = *(const float4*)&W3[t * (8*NTOW) + 8*t + 4*kg];
  w.a3 = cvt4n(v3);

  // c1 = b1 rows 4kg..4kg+3 (rows 12..15 structurally zero).
  float4 vb1 = {0.f, 0.f, 0.f, 0.f};
  if (kg < 3) vb1 = *(const float4*)&B1[12*t + 4*kg];
  w.c1 = (f4_t){vb1.x, vb1.y, vb1.z, vb1.w};

  // c2 = b2 rows 4kg..4kg+3 (rows 8..15 structurally zero).
  float4 vb2 = {0.f, 0.f, 0.f, 0.f};
  if (kg < 2) vb2 = *(const float4*)&B2[8*t + 4*kg];
  w.c2 = (f4_t){vb2.x, vb2.y, vb2.z, vb2.w};
  return w;
}

#define MFMA16(A, B, C) __builtin_amdgcn_mfma_f32_16x16x16f16((A), (B), (C), 0, 0, 0)

// Four towers x TWO sample tiles, layers in lockstep: each layer step
// issues 8 independent MFMAs + 8 relus -> 8-way ILP covers the
// MFMA->relu->MFMA dependency latency. All values named (SSA).
// Returns {sumA, sumB} (lane row 0 only is nonzero).
static __device__ __forceinline__ float2 oct_chain(
    h4_t a0_0, h4_t a1_0, h4_t a2_0, h4_t a3_0, f4_t c1_0, f4_t c2_0,
    h4_t a0_1, h4_t a1_1, h4_t a2_1, h4_t a3_1, f4_t c1_1, f4_t c2_1,
    h4_t a0_2, h4_t a1_2, h4_t a2_2, h4_t a3_2, f4_t c1_2, f4_t c2_2,
    h4_t a0_3, h4_t a1_3, h4_t a2_3, h4_t a3_3, f4_t c1_3, f4_t c2_3,
    h4_t bA, h4_t bB) {
  const f4_t zc = {0.f, 0.f, 0.f, 0.f};
  const f4_t dA0_0 = MFMA16(a0_0, bA, zc);
  const f4_t dB0_0 = MFMA16(a0_0, bB, zc);
  const f4_t dA0_1 = MFMA16(a0_1, bA, zc);
  const f4_t dB0_1 = MFMA16(a0_1, bB, zc);
  const f4_t dA0_2 = MFMA16(a0_2, bA, zc);
  const f4_t dB0_2 = MFMA16(a0_2, bB, zc);
  const f4_t dA0_3 = MFMA16(a0_3, bA, zc);
  const f4_t dB0_3 = MFMA16(a0_3, bB, zc);
  const h4_t hA0_0 = relu_pack4(dA0_0);
  const h4_t hB0_0 = relu_pack4(dB0_0);
  const h4_t hA0_1 = relu_pack4(dA0_1);
  const h4_t hB0_1 = relu_pack4(dB0_1);
  const h4_t hA0_2 = relu_pack4(dA0_2);
  const h4_t hB0_2 = relu_pack4(dB0_2);
  const h4_t hA0_3 = relu_pack4(dA0_3);
  const h4_t hB0_3 = relu_pack4(dB0_3);
  const f4_t dA1_0 = MFMA16(a1_0, hA0_0, c1_0);
  const f4_t dB1_0 = MFMA16(a1_0, hB0_0, c1_0);
  const f4_t dA1_1 = MFMA16(a1_1, hA0_1, c1_1);
  const f4_t dB1_1 = MFMA16(a1_1, hB0_1, c1_1);
  const f4_t dA1_2 = MFMA16(a1_2, hA0_2, c1_2);
  const f4_t dB1_2 = MFMA16(a1_2, hB0_2, c1_2);
  const f4_t dA1_3 = MFMA16(a1_3, hA0_3, c1_3);
  const f4_t dB1_3 = MFMA16(a1_3, hB0_3, c1_3);
  const h4_t hA1_0 = relu_pack4(dA1_0);
  const h4_t hB1_0 = relu_pack4(dB1_0);
  const h4_t hA1_1 = relu_pack4(dA1_1);
  const h4_t hB1_1 = relu_pack4(dB1_1);
  const h4_t hA1_2 = relu_pack4(dA1_2);
  const h4_t hB1_2 = relu_pack4(dB1_2);
  const h4_t hA1_3 = relu_pack4(dA1_3);
  const h4_t hB1_3 = relu_pack4(dB1_3);
  const f4_t dA2_0 = MFMA16(a2_0, hA1_0, c2_0);
  const f4_t dB2_0 = MFMA16(a2_0, hB1_0, c2_0);
  const f4_t dA2_1 = MFMA16(a2_1, hA1_1, c2_1);
  const f4_t dB2_1 = MFMA16(a2_1, hB1_1, c2_1);
  const f4_t dA2_2 = MFMA16(a2_2, hA1_2, c2_2);
  const f4_t dB2_2 = MFMA16(a2_2, hB1_2, c2_2);
  const f4_t dA2_3 = MFMA16(a2_3, hA1_3, c2_3);
  const f4_t dB2_3 = MFMA16(a2_3, hB1_3, c2_3);
  const h4_t hA2_0 = relu_pack4(dA2_0);
  const h4_t hB2_0 = relu_pack4(dB2_0);
  const h4_t hA2_1 = relu_pack4(dA2_1);
  const h4_t hB2_1 = relu_pack4(dB2_1);
  const h4_t hA2_2 = relu_pack4(dA2_2);
  const h4_t hB2_2 = relu_pack4(dB2_2);
  const h4_t hA2_3 = relu_pack4(dA2_3);
  const h4_t hB2_3 = relu_pack4(dB2_3);
  const f4_t dA3_0 = MFMA16(a3_0, hA2_0, zc);
  const f4_t dB3_0 = MFMA16(a3_0, hB2_0, zc);
  const f4_t dA3_1 = MFMA16(a3_1, hA2_1, zc);
  const f4_t dB3_1 = MFMA16(a3_1, hB2_1, zc);
  const f4_t dA3_2 = MFMA16(a3_2, hA2_2, zc);
  const f4_t dB3_2 = MFMA16(a3_2, hB2_2, zc);
  const f4_t dA3_3 = MFMA16(a3_3, hA2_3, zc);
  const f4_t dB3_3 = MFMA16(a3_3, hB2_3, zc);
  // Only row 0 (kg==0, reg 0) of each L3 product is nonzero.
  float2 r;
  r.x = (dA3_0[0] + dA3_1[0]) + (dA3_2[0] + dA3_3[0]);
  r.y = (dB3_0[0] + dB3_1[0]) + (dB3_2[0] + dB3_3[0]);
  return r;
}

// One block: tower group g (16 towers) x 256 samples (4 waves x 64).
// All 4 waves gather/stream the SAME 16 towers' weights -> L1/L2 reuse.
__global__ __launch_bounds__(256, 4) void bs_fused(
    const float* __restrict__ x,
    const float* __restrict__ W0, const float* __restrict__ B0,
    const float* __restrict__ W1, const float* __restrict__ B1,
    const float* __restrict__ W2, const float* __restrict__ B2,
    const float* __restrict__ W3, const float* __restrict__ B3,
    const float* __restrict__ bias,
    float* __restrict__ out) {
  const int warp  = threadIdx.x >> 6;
  const int lane  = threadIdx.x & 63;
  const int col   = lane & 15;       // sample within tile
  const int kg    = lane >> 4;
  const int row   = col;             // A-frag row = lane&15
  const int g     = blockIdx.x & 7;  // tower group: towers [16g, 16g+16)
  const int tile  = blockIdx.x >> 3;
  const int sbase = tile * 256 + warp * 64;

  // sum(b3) + bias: only g==0 blocks need it; 2 loads + wave reduce.
  float cbias = 0.f;
  if (g == 0) {
    float s = B3[lane] + B3[64 + lane];
#pragma unroll
    for (int m = 32; m >= 1; m >>= 1) s += __shfl_xor(s, m);
    cbias = s + bias[0];
  }

  // Per-lane x base: sample row (sbase+col), feature 2*(16g + kg).
  const float* __restrict__ xb =
      x + (size_t)(sbase + col) * FEAT + 2 * (g * 16 + kg);

  float acc0 = 0.f, acc1 = 0.f, acc2 = 0.f, acc3 = 0.f;

#pragma unroll 1
  for (int p = 0; p < 4; ++p) {      // packs of 4 towers — ROLLED
    // B0 fragments for this pack's 4 sample tiles (shared by the pack's
    // 4 towers). Named scalars -> guaranteed register allocation.
    const float* __restrict__ xp = xb + 8 * p;
    const h4_t bq0 = make_b0(xp + (size_t)0 * 16 * FEAT);
    const h4_t bq1 = make_b0(xp + (size_t)1 * 16 * FEAT);
    const h4_t bq2 = make_b0(xp + (size_t)2 * 16 * FEAT);
    const h4_t bq3 = make_b0(xp + (size_t)3 * 16 * FEAT);

    // Gather this pack's 4 towers directly from raw weights.
    const int tb = g * 16 + 4 * p;
    const TW t0 = gather_tower(tb + 0, row, kg, W0, B0, W1, B1, W2, B2, W3);
    const TW t1 = gather_tower(tb + 1, row, kg, W0, B0, W1, B1, W2, B2, W3);
    const TW t2 = gather_tower(tb + 2, row, kg, W0, B0, W1, B1, W2, B2, W3);
    const TW t3 = gather_tower(tb + 3, row, kg, W0, B0, W1, B1, W2, B2, W3);

    const float2 r01 = oct_chain(t0.a0, t0.a1, t0.a2, t0.a3, t0.c1, t0.c2,
                                 t1.a0, t1.a1, t1.a2, t1.a3, t1.c1, t1.c2,
                                 t2.a0, t2.a1, t2.a2, t2.a3, t2.c1, t2.c2,
                                 t3.a0, t3.a1, t3.a2, t3.a3, t3.c1, t3.c2,
                                 bq0, bq1);
    acc0 += r01.x; acc1 += r01.y;
    const float2 r23 = oct_chain(t0.a0, t0.a1, t0.a2, t0.a3, t0.c1, t0.c2,
                                 t1.a0, t1.a1, t1.a2, t1.a3, t1.c1, t1.c2,
                                 t2.a0, t2.a1, t2.a2, t2.a3, t2.c1, t2.c2,
                                 t3.a0, t3.a1, t3.a2, t3.a3, t3.c1, t3.c2,
                                 bq2, bq3);
    acc2 += r23.x; acc3 += r23.y;
  }

  if (kg == 0) {
    const float add = (g == 0) ? cbias : 0.f;
    atomicAdd(out + sbase +  0 + col, acc0 + add);
    atomicAdd(out + sbase + 16 + col, acc1 + add);
    atomicAdd(out + sbase + 32 + col, acc2 + add);
    atomicAdd(out + sbase + 48 + col, acc3 + add);
  }
}

extern "C" void kernel_launch(void* const* d_in, const int* in_sizes, int n_in,
                              void* d_out, int out_size, void* d_ws, size_t ws_size,
                              hipStream_t stream) {
  const float* x    = (const float*)d_in[0];
  const float* W0   = (const float*)d_in[1];
  const float* B0   = (const float*)d_in[2];
  const float* W1   = (const float*)d_in[3];
  const float* B1   = (const float*)d_in[4];
  const float* W2   = (const float*)d_in[5];
  const float* B2   = (const float*)d_in[6];
  const float* W3   = (const float*)d_in[7];
  const float* B3   = (const float*)d_in[8];
  const float* bias = (const float*)d_in[9];
  float* out = (float*)d_out;

  // Zero out[0:BATCH] (accumulated by atomics) + shape_loss tail.
  (void)hipMemsetAsync(d_out, 0, (size_t)out_size * sizeof(float), stream);

  const int blocks = (BATCH / 256) * 8;           // 1024 blocks
  bs_fused<<<blocks, 256, 0, stream>>>(x, W0, B0, W1, B1, W2, B2, W3, B3,
                                       bias, out);
}

// Round 23
// 29.232 us; speedup vs baseline: 2.8392x; 2.8392x over previous
//
#include <hip/hip_runtime.h>
#include <stdint.h>

// Blocksparse Deep ReLU GAM forward via chained f16 MFMA.
// 128 towers, each 2->16->12->8->1 MLP over input pair (2t, 2t+1);
// out[s] = sum_t tower_t(x[s]) + bias. shape_loss output = zeros(128).
//
// FINAL (r23 = r21, the measured best at 29.21us). r22's fused direct-
// gather variant regressed to 83us (scratch spill WRITE 53MB + 135MB of
// uncoalesced raw-weight re-fetch) — the pack kernel exists to amortize
// the fragment gather once instead of per tile-block. Reverted.
//
// v_mfma_f32_16x16x16_f16 D layout (row=(lane>>4)*4+reg, col=lane&15)
// equals the B layout (k=(lane>>4)*4+i, col=lane&15), so Y = W·X chains
// layer-to-layer with only lane-local relu + f32->f16 cvt.
//
// Structure (each element verified by within-session A/B):
//  - pack_frags: one 64-lane block per tower gathers the tower's MFMA
//    A-fragments + C-operand biases into a 2176B record; also zeroes
//    out[] and wave-reduces sum(b3)+bias.
//  - bs_mfma: block = (tower group g of 16) x (256 samples, 4 waves).
//    Same-g blocks -> all 4 waves stream the same 16 records (L1).
//    Rolled pack loop (4 towers/iter) fences liveness; all values are
//    named scalars (arrays -> scratch, rule #20; full unroll -> 200
//    VGPR). oct_chain: 4 towers x 2 sample tiles in lockstep = 8
//    independent MFMAs per layer step to cover chain latency.
//  - 4-tower shared B0: lane (kg,col) carries B0 rows 4kg..4kg+2 =
//    {x[s][2(tb+kg)], x[s][2(tb+kg)+1], 1}; tower tb+j's A0 is nonzero
//    only in k-cols 4j..4j+2 -> one coalesced x load feeds 4 towers.
//  - Bias: b0 -> A0 k=4j+2 (homogeneous coord); b1 -> C of L1 MFMA;
//    b2 -> C of L2 MFMA; sum(b3)+bias -> one scalar at the end.

constexpr int BATCH = 32768;
constexpr int FEAT  = 256;
constexpr int NTOW  = 128;
constexpr int OUTN  = BATCH + NTOW;   // out + shape_loss

constexpr int REC = 544;  // dwords per tower record (2176 B, 16B-aligned)
// [0,512) = 64 lanes x 8 dwords {a0.lo,a0.hi,a1.lo,a1.hi,a2.lo,a2.hi,
// a3.lo,a3.hi}; [512,544) = bb: per kg {b1[4kg..4kg+3], b2[4kg..4kg+3]}.
constexpr int OFF_BB = 512;

typedef _Float16 h4_t __attribute__((ext_vector_type(4)));
typedef __fp16   hp2_t __attribute__((ext_vector_type(2)));
typedef float    f4_t __attribute__((ext_vector_type(4)));

static __device__ __forceinline__ h4_t u2_to_h4(uint32_t lo, uint32_t hi) {
  union { uint2 u; h4_t h; } cv; cv.u.x = lo; cv.u.y = hi; return cv.h;
}
static __device__ __forceinline__ void h4_to_u2(h4_t v, uint32_t* d) {
  union { h4_t h; uint2 u; } cv; cv.h = v; d[0] = cv.u.x; d[1] = cv.u.y;
}
// pack 4 f32 -> 4 f16 (2x v_cvt_pkrtz) then packed relu (v_pk_max_f16 x2).
// relu(cvt(x)) == cvt(relu(x)): RTZ preserves sign; -0 is harmless in dots.
static __device__ __forceinline__ h4_t relu_pack4(const f4_t d) {
  const hp2_t lo = __builtin_amdgcn_cvt_pkrtz(d[0], d[1]);
  const hp2_t hi = __builtin_amdgcn_cvt_pkrtz(d[2], d[3]);
  h4_t r;
  r[0] = (_Float16)lo[0]; r[1] = (_Float16)lo[1];
  r[2] = (_Float16)hi[0]; r[3] = (_Float16)hi[1];
  const h4_t z = {(_Float16)0.f, (_Float16)0.f, (_Float16)0.f, (_Float16)0.f};
  return __builtin_elementwise_max(r, z);
}
// Build a B0 fragment from an x pair: {x0, x1, 1, 0}.
static __device__ __forceinline__ h4_t make_b0(const float* __restrict__ p) {
  const float2 xv = *(const float2*)p;
  const hp2_t xh = __builtin_amdgcn_cvt_pkrtz(xv.x, xv.y);
  h4_t b;
  b[0] = (_Float16)xh[0]; b[1] = (_Float16)xh[1];
  b[2] = (_Float16)1.0f;  b[3] = (_Float16)0.0f;
  return b;
}

#define MFMA16(A, B, C) __builtin_amdgcn_mfma_f32_16x16x16f16((A), (B), (C), 0, 0, 0)

// Four towers x TWO sample tiles, layers in lockstep: each layer step
// issues 8 independent MFMAs + 8 relus -> 8-way ILP covers the
// MFMA->relu->MFMA dependency latency. All values named (SSA).
// Returns {sumA, sumB} (lane row 0 only is nonzero).
static __device__ __forceinline__ float2 oct_chain(
    h4_t a0_0, h4_t a1_0, h4_t a2_0, h4_t a3_0, f4_t c1_0, f4_t c2_0,
    h4_t a0_1, h4_t a1_1, h4_t a2_1, h4_t a3_1, f4_t c1_1, f4_t c2_1,
    h4_t a0_2, h4_t a1_2, h4_t a2_2, h4_t a3_2, f4_t c1_2, f4_t c2_2,
    h4_t a0_3, h4_t a1_3, h4_t a2_3, h4_t a3_3, f4_t c1_3, f4_t c2_3,
    h4_t bA, h4_t bB) {
  const f4_t zc = {0.f, 0.f, 0.f, 0.f};
  const f4_t dA0_0 = MFMA16(a0_0, bA, zc);
  const f4_t dB0_0 = MFMA16(a0_0, bB, zc);
  const f4_t dA0_1 = MFMA16(a0_1, bA, zc);
  const f4_t dB0_1 = MFMA16(a0_1, bB, zc);
  const f4_t dA0_2 = MFMA16(a0_2, bA, zc);
  const f4_t dB0_2 = MFMA16(a0_2, bB, zc);
  const f4_t dA0_3 = MFMA16(a0_3, bA, zc);
  const f4_t dB0_3 = MFMA16(a0_3, bB, zc);
  const h4_t hA0_0 = relu_pack4(dA0_0);
  const h4_t hB0_0 = relu_pack4(dB0_0);
  const h4_t hA0_1 = relu_pack4(dA0_1);
  const h4_t hB0_1 = relu_pack4(dB0_1);
  const h4_t hA0_2 = relu_pack4(dA0_2);
  const h4_t hB0_2 = relu_pack4(dB0_2);
  const h4_t hA0_3 = relu_pack4(dA0_3);
  const h4_t hB0_3 = relu_pack4(dB0_3);
  const f4_t dA1_0 = MFMA16(a1_0, hA0_0, c1_0);
  const f4_t dB1_0 = MFMA16(a1_0, hB0_0, c1_0);
  const f4_t dA1_1 = MFMA16(a1_1, hA0_1, c1_1);
  const f4_t dB1_1 = MFMA16(a1_1, hB0_1, c1_1);
  const f4_t dA1_2 = MFMA16(a1_2, hA0_2, c1_2);
  const f4_t dB1_2 = MFMA16(a1_2, hB0_2, c1_2);
  const f4_t dA1_3 = MFMA16(a1_3, hA0_3, c1_3);
  const f4_t dB1_3 = MFMA16(a1_3, hB0_3, c1_3);
  const h4_t hA1_0 = relu_pack4(dA1_0);
  const h4_t hB1_0 = relu_pack4(dB1_0);
  const h4_t hA1_1 = relu_pack4(dA1_1);
  const h4_t hB1_1 = relu_pack4(dB1_1);
  const h4_t hA1_2 = relu_pack4(dA1_2);
  const h4_t hB1_2 = relu_pack4(dB1_2);
  const h4_t hA1_3 = relu_pack4(dA1_3);
  const h4_t hB1_3 = relu_pack4(dB1_3);
  const f4_t dA2_0 = MFMA16(a2_0, hA1_0, c2_0);
  const f4_t dB2_0 = MFMA16(a2_0, hB1_0, c2_0);
  const f4_t dA2_1 = MFMA16(a2_1, hA1_1, c2_1);
  const f4_t dB2_1 = MFMA16(a2_1, hB1_1, c2_1);
  const f4_t dA2_2 = MFMA16(a2_2, hA1_2, c2_2);
  const f4_t dB2_2 = MFMA16(a2_2, hB1_2, c2_2);
  const f4_t dA2_3 = MFMA16(a2_3, hA1_3, c2_3);
  const f4_t dB2_3 = MFMA16(a2_3, hB1_3, c2_3);
  const h4_t hA2_0 = relu_pack4(dA2_0);
  const h4_t hB2_0 = relu_pack4(dB2_0);
  const h4_t hA2_1 = relu_pack4(dA2_1);
  const h4_t hB2_1 = relu_pack4(dB2_1);
  const h4_t hA2_2 = relu_pack4(dA2_2);
  const h4_t hB2_2 = relu_pack4(dB2_2);
  const h4_t hA2_3 = relu_pack4(dA2_3);
  const h4_t hB2_3 = relu_pack4(dB2_3);
  const f4_t dA3_0 = MFMA16(a3_0, hA2_0, zc);
  const f4_t dB3_0 = MFMA16(a3_0, hB2_0, zc);
  const f4_t dA3_1 = MFMA16(a3_1, hA2_1, zc);
  const f4_t dB3_1 = MFMA16(a3_1, hB2_1, zc);
  const f4_t dA3_2 = MFMA16(a3_2, hA2_2, zc);
  const f4_t dB3_2 = MFMA16(a3_2, hB2_2, zc);
  const f4_t dA3_3 = MFMA16(a3_3, hA2_3, zc);
  const f4_t dB3_3 = MFMA16(a3_3, hB2_3, zc);
  // Only row 0 (kg==0, reg 0) of each L3 product is nonzero.
  float2 r;
  r.x = (dA3_0[0] + dA3_1[0]) + (dA3_2[0] + dA3_3[0]);
  r.y = (dB3_0[0] + dB3_1[0]) + (dB3_2[0] + dB3_3[0]);
  return r;
}

__global__ void pack_frags(
    const float* __restrict__ W0, const float* __restrict__ B0,
    const float* __restrict__ W1, const float* __restrict__ B1,
    const float* __restrict__ W2, const float* __restrict__ B2,
    const float* __restrict__ W3, const float* __restrict__ B3,
    const float* __restrict__ bias, uint32_t* __restrict__ pack,
    float* __restrict__ out) {
  const int t   = blockIdx.x;
  const int l   = threadIdx.x;      // 64 threads = 64 lanes
  const int row = l & 15;           // A-frag row  = lane&15
  const int kg  = l >> 4;           // A-frag k    = (lane>>4)*4 + r
  uint32_t* rec = pack + t * REC;

  // Zero the output buffer (out[0:BATCH] accumulated by atomics;
  // shape_loss[BATCH:BATCH+NTOW] stays 0). Grid-stride over all blocks.
  for (int i = t * 64 + l; i < OUTN; i += NTOW * 64) out[i] = 0.f;

  h4_t a0, a1, a2, a3;
#pragma unroll
  for (int r = 0; r < 4; ++r) {
    const int k = kg * 4 + r;
    // A0: tower t occupies k-columns 4*(t&3) .. 4*(t&3)+2.
    float v0 = 0.f;
    if (kg == (t & 3)) {
      if (r < 2)       v0 = W0[(16*t + row) * FEAT + 2*t + r];
      else if (r == 2) v0 = B0[16*t + row];
    }
    a0[r] = (_Float16)v0;

    float v1 = 0.f;
    if (row < 12)    v1 = W1[(12*t + row) * (16*NTOW) + 16*t + k];
    a1[r] = (_Float16)v1;

    float v2 = 0.f;
    if (row < 8 && k < 12) v2 = W2[(8*t + row) * (12*NTOW) + 12*t + k];
    a2[r] = (_Float16)v2;

    float v3 = 0.f;
    if (row == 0 && k < 8) v3 = W3[t * (8*NTOW) + 8*t + k];
    a3[r] = (_Float16)v3;
  }
  uint32_t* lrec = rec + 8 * l;
  h4_to_u2(a0, lrec + 0);
  h4_to_u2(a1, lrec + 2);
  h4_to_u2(a2, lrec + 4);
  h4_to_u2(a3, lrec + 6);

  if (l < 16) {
    // Interleaved bb layout: per kg-group {b1[4kg..4kg+3], b2[...]}.
    const float b1v = (l < 12) ? B1[12*t + l] : 0.f;
    const float b2v = (l < 8) ? B2[8*t + l] : 0.f;
    rec[OFF_BB + (l >> 2) * 8 +     (l & 3)] = __float_as_uint(b1v);
    rec[OFF_BB + (l >> 2) * 8 + 4 + (l & 3)] = __float_as_uint(b2v);
  }
  if (t == 0) {
    // Parallel b3+bias sum: 64 lanes load 2 each, wave shuffle-reduce.
    float s = B3[l] + B3[64 + l];
#pragma unroll
    for (int m = 32; m >= 1; m >>= 1) s += __shfl_xor(s, m);
    if (l == 0) pack[NTOW * REC] = __float_as_uint(s + bias[0]);
  }
}

// One block: tower group g (16 towers) x 256 samples (4 waves x 64).
// All 4 waves stream the SAME 16 tower records -> L1-resident weights.
__global__ __launch_bounds__(256, 4) void bs_mfma(
    const float* __restrict__ x, const uint32_t* __restrict__ pack,
    float* __restrict__ out) {
  const int warp  = threadIdx.x >> 6;
  const int lane  = threadIdx.x & 63;
  const int col   = lane & 15;       // sample within tile
  const int kg    = lane >> 4;
  const int g     = blockIdx.x & 7;  // tower group: towers [16g, 16g+16)
  const int tile  = blockIdx.x >> 3;
  const int sbase = tile * 256 + warp * 64;

  const float cbias = __uint_as_float(pack[NTOW * REC]);

  // Per-lane x base: sample row (sbase+col), feature 2*(16g + kg).
  const float* __restrict__ xb =
      x + (size_t)(sbase + col) * FEAT + 2 * (g * 16 + kg);

  const uint32_t* __restrict__ fp = pack + (size_t)(g * 16) * REC + 8 * lane;
  const uint32_t* __restrict__ bp = pack + (size_t)(g * 16) * REC + OFF_BB + kg * 8;

  float acc0 = 0.f, acc1 = 0.f, acc2 = 0.f, acc3 = 0.f;

#pragma unroll 1
  for (int p = 0; p < 4; ++p) {      // packs of 4 towers — ROLLED
    // B0 fragments for this pack's 4 sample tiles (shared by the pack's
    // 4 towers). Named scalars -> guaranteed register allocation.
    const float* __restrict__ xp = xb + 8 * p;
    const h4_t bq0 = make_b0(xp + (size_t)0 * 16 * FEAT);
    const h4_t bq1 = make_b0(xp + (size_t)1 * 16 * FEAT);
    const h4_t bq2 = make_b0(xp + (size_t)2 * 16 * FEAT);
    const h4_t bq3 = make_b0(xp + (size_t)3 * 16 * FEAT);

    // Load all 4 towers' fragments (named; ~64 VGPR of weight state).
    const uint32_t* __restrict__ fpp = fp + (size_t)(4 * p) * REC;
    const uint32_t* __restrict__ bpp = bp + (size_t)(4 * p) * REC;
    const uint4  w01_0 = *(const uint4*)(fpp + 0 * REC);
    const uint4  w23_0 = *(const uint4*)(fpp + 0 * REC + 4);
    const uint4  w01_1 = *(const uint4*)(fpp + 1 * REC);
    const uint4  w23_1 = *(const uint4*)(fpp + 1 * REC + 4);
    const uint4  w01_2 = *(const uint4*)(fpp + 2 * REC);
    const uint4  w23_2 = *(const uint4*)(fpp + 2 * REC + 4);
    const uint4  w01_3 = *(const uint4*)(fpp + 3 * REC);
    const uint4  w23_3 = *(const uint4*)(fpp + 3 * REC + 4);
    const float4 bbA_0 = *(const float4*)(bpp + 0 * REC);
    const float4 bbB_0 = *(const float4*)(bpp + 0 * REC + 4);
    const float4 bbA_1 = *(const float4*)(bpp + 1 * REC);
    const float4 bbB_1 = *(const float4*)(bpp + 1 * REC + 4);
    const float4 bbA_2 = *(const float4*)(bpp + 2 * REC);
    const float4 bbB_2 = *(const float4*)(bpp + 2 * REC + 4);
    const float4 bbA_3 = *(const float4*)(bpp + 3 * REC);
    const float4 bbB_3 = *(const float4*)(bpp + 3 * REC + 4);

    const h4_t a0_0 = u2_to_h4(w01_0.x, w01_0.y), a1_0 = u2_to_h4(w01_0.z, w01_0.w);
    const h4_t a2_0 = u2_to_h4(w23_0.x, w23_0.y), a3_0 = u2_to_h4(w23_0.z, w23_0.w);
    const h4_t a0_1 = u2_to_h4(w01_1.x, w01_1.y), a1_1 = u2_to_h4(w01_1.z, w01_1.w);
    const h4_t a2_1 = u2_to_h4(w23_1.x, w23_1.y), a3_1 = u2_to_h4(w23_1.z, w23_1.w);
    const h4_t a0_2 = u2_to_h4(w01_2.x, w01_2.y), a1_2 = u2_to_h4(w01_2.z, w01_2.w);
    const h4_t a2_2 = u2_to_h4(w23_2.x, w23_2.y), a3_2 = u2_to_h4(w23_2.z, w23_2.w);
    const h4_t a0_3 = u2_to_h4(w01_3.x, w01_3.y), a1_3 = u2_to_h4(w01_3.z, w01_3.w);
    const h4_t a2_3 = u2_to_h4(w23_3.x, w23_3.y), a3_3 = u2_to_h4(w23_3.z, w23_3.w);
    const f4_t c1_0 = {bbA_0.x, bbA_0.y, bbA_0.z, bbA_0.w};
    const f4_t c2_0 = {bbB_0.x, bbB_0.y, bbB_0.z, bbB_0.w};
    const f4_t c1_1 = {bbA_1.x, bbA_1.y, bbA_1.z, bbA_1.w};
    const f4_t c2_1 = {bbB_1.x, bbB_1.y, bbB_1.z, bbB_1.w};
    const f4_t c1_2 = {bbA_2.x, bbA_2.y, bbA_2.z, bbA_2.w};
    const f4_t c2_2 = {bbB_2.x, bbB_2.y, bbB_2.z, bbB_2.w};
    const f4_t c1_3 = {bbA_3.x, bbA_3.y, bbA_3.z, bbA_3.w};
    const f4_t c2_3 = {bbB_3.x, bbB_3.y, bbB_3.z, bbB_3.w};

    const float2 r01 = oct_chain(a0_0, a1_0, a2_0, a3_0, c1_0, c2_0,
                                 a0_1, a1_1, a2_1, a3_1, c1_1, c2_1,
                                 a0_2, a1_2, a2_2, a3_2, c1_2, c2_2,
                                 a0_3, a1_3, a2_3, a3_3, c1_3, c2_3,
                                 bq0, bq1);
    acc0 += r01.x; acc1 += r01.y;
    const float2 r23 = oct_chain(a0_0, a1_0, a2_0, a3_0, c1_0, c2_0,
                                 a0_1, a1_1, a2_1, a3_1, c1_1, c2_1,
                                 a0_2, a1_2, a2_2, a3_2, c1_2, c2_2,
                                 a0_3, a1_3, a2_3, a3_3, c1_3, c2_3,
                                 bq2, bq3);
    acc2 += r23.x; acc3 += r23.y;
  }

  if (kg == 0) {
    const float add = (g == 0) ? cbias : 0.f;
    atomicAdd(out + sbase +  0 + col, acc0 + add);
    atomicAdd(out + sbase + 16 + col, acc1 + add);
    atomicAdd(out + sbase + 32 + col, acc2 + add);
    atomicAdd(out + sbase + 48 + col, acc3 + add);
  }
}

// ---- correctness-only fallback (ws too small; never expected) ----
__device__ __forceinline__ float gather_weight(
    int t, int i,
    const float* __restrict__ W0, const float* __restrict__ B0,
    const float* __restrict__ W1, const float* __restrict__ B1,
    const float* __restrict__ W2, const float* __restrict__ B2,
    const float* __restrict__ W3, const float* __restrict__ B3) {
  float v = 0.f;
  if (i < 32)       { int r = i >> 1, c = i & 1;               v = W0[(16*t + r)*FEAT + 2*t + c]; }
  else if (i < 48)  {                                           v = B0[16*t + (i - 32)]; }
  else if (i < 240) { int k = i - 48, r = k >> 4, c = k & 15;   v = W1[(12*t + r)*(16*NTOW) + 16*t + c]; }
  else if (i < 252) {                                           v = B1[12*t + (i - 240)]; }
  else if (i < 348) { int k = i - 252, r = k / 12, c = k - 12*r; v = W2[(8*t + r)*(12*NTOW) + 12*t + c]; }
  else if (i < 356) {                                           v = B2[8*t + (i - 348)]; }
  else if (i < 364) {                                           v = W3[t*(8*NTOW) + 8*t + (i - 356)]; }
  else if (i == 364){                                           v = B3[t]; }
  return v;
}

__global__ void bs_fwd_slow(
    const float* __restrict__ x,
    const float* __restrict__ W0, const float* __restrict__ B0,
    const float* __restrict__ W1, const float* __restrict__ B1,
    const float* __restrict__ W2, const float* __restrict__ B2,
    const float* __restrict__ W3, const float* __restrict__ B3,
    const float* __restrict__ bias,
    float* __restrict__ out) {
  const int s = blockIdx.x * blockDim.x + threadIdx.x;
  if (s >= BATCH) return;
  float acc = bias[0];
  for (int t = 0; t < NTOW; ++t) {
    float h0[16], h1[12], h2[8];
    const float x0 = x[(size_t)s*FEAT + 2*t], x1 = x[(size_t)s*FEAT + 2*t + 1];
    for (int r = 0; r < 16; ++r)
      h0[r] = fmaxf(0.f, gather_weight(t, 2*r, W0,B0,W1,B1,W2,B2,W3,B3) * x0
                        + gather_weight(t, 2*r+1, W0,B0,W1,B1,W2,B2,W3,B3) * x1
                        + gather_weight(t, 32+r, W0,B0,W1,B1,W2,B2,W3,B3));
    for (int r = 0; r < 12; ++r) {
      float sum = gather_weight(t, 240+r, W0,B0,W1,B1,W2,B2,W3,B3);
      for (int c = 0; c < 16; ++c)
        sum += gather_weight(t, 48+16*r+c, W0,B0,W1,B1,W2,B2,W3,B3) * h0[c];
      h1[r] = fmaxf(0.f, sum);
    }
    for (int r = 0; r < 8; ++r) {
      float sum = gather_weight(t, 348+r, W0,B0,W1,B1,W2,B2,W3,B3);
      for (int c = 0; c < 12; ++c)
        sum += gather_weight(t, 252+12*r+c, W0,B0,W1,B1,W2,B2,W3,B3) * h1[c];
      h2[r] = fmaxf(0.f, sum);
    }
    float sum = gather_weight(t, 364, W0,B0,W1,B1,W2,B2,W3,B3);
    for (int c = 0; c < 8; ++c)
      sum += gather_weight(t, 356+c, W0,B0,W1,B1,W2,B2,W3,B3) * h2[c];
    acc += sum;
  }
  out[s] = acc;
}

extern "C" void kernel_launch(void* const* d_in, const int* in_sizes, int n_in,
                              void* d_out, int out_size, void* d_ws, size_t ws_size,
                              hipStream_t stream) {
  const float* x    = (const float*)d_in[0];
  const float* W0   = (const float*)d_in[1];
  const float* B0   = (const float*)d_in[2];
  const float* W1   = (const float*)d_in[3];
  const float* B1   = (const float*)d_in[4];
  const float* W2   = (const float*)d_in[5];
  const float* B2   = (const float*)d_in[6];
  const float* W3   = (const float*)d_in[7];
  const float* B3   = (const float*)d_in[8];
  const float* bias = (const float*)d_in[9];
  float* out = (float*)d_out;

  const size_t packBytes = ((size_t)NTOW * REC + 1) * sizeof(uint32_t);

  if (ws_size >= packBytes) {
    uint32_t* pack = (uint32_t*)d_ws;
    // pack_frags also zeroes out[] (atomics accumulate; shape_loss stays 0).
    pack_frags<<<NTOW, 64, 0, stream>>>(W0, B0, W1, B1, W2, B2, W3, B3, bias, pack, out);
    const int blocks = (BATCH / 256) * 8;         // 1024 blocks
    bs_mfma<<<blocks, 256, 0, stream>>>(x, pack, out);
  } else {
    (void)hipMemsetAsync(d_out, 0, (size_t)out_size * sizeof(float), stream);
    bs_fwd_slow<<<BATCH / 256, 256, 0, stream>>>(x, W0, B0, W1, B1, W2, B2, W3, B3, bias, out);
  }
}